// Round 1
// 553.804 us; speedup vs baseline: 1.1487x; 1.1487x over previous
//
// R6: GEMM rewritten to the 256x256 8-phase counted-vmcnt template (T3+T4)
// with T2 LDS XOR-swizzle (rule 21: linear gload_lds dest + inverse-swizzled
// global source + swizzled ds_read) and T5 setprio. decode/fwht unchanged.
#include <hip/hip_runtime.h>
#include <hip/hip_fp16.h>

typedef _Float16 half8 __attribute__((ext_vector_type(8)));
typedef _Float16 half4v __attribute__((ext_vector_type(4)));
typedef float floatx4 __attribute__((ext_vector_type(4)));

#define K_DIM 4096   // inner dim (d_in)
#define N_DIM 4096   // output features (m)
#define B_ROWS 8192  // batch rows (4*2048)

#define BM 256
#define BN 256
#define BK 64
#define NTILES (K_DIM / BK)  // 64

// ---------------- 1. decode: W[j] = f16(D4_CB[Qidxs[j]]) --------------------
__global__ __launch_bounds__(256) void decode_kernel(
    const int* __restrict__ qidxs, const float4* __restrict__ cb,
    half4v* __restrict__ w) {
  int i = blockIdx.x * 256 + threadIdx.x;
  float4 v = cb[qidxs[i]];
  half4v h;
  h.x = (_Float16)v.x;
  h.y = (_Float16)v.y;
  h.z = (_Float16)v.z;
  h.w = (_Float16)v.w;
  w[i] = h;
}

// ---------------- 2. fwht over input rows -> f16 ----------------------------
__global__ __launch_bounds__(256) void fwht_in_kernel(
    const float* __restrict__ x, const float* __restrict__ su,
    _Float16* __restrict__ out) {
  __shared__ float s[4096];
  const int t = threadIdx.x;
  const float4* xv = (const float4*)(x + (size_t)blockIdx.x * 4096);
  const float4* uv = (const float4*)su;
  for (int i = t; i < 1024; i += 256) {
    float4 v = xv[i], u = uv[i];
    s[4 * i + 0] = v.x * u.x;
    s[4 * i + 1] = v.y * u.y;
    s[4 * i + 2] = v.z * u.z;
    s[4 * i + 3] = v.w * u.w;
  }
  __syncthreads();
  for (int h = 1; h < 4096; h <<= 1) {
    for (int j = t; j < 2048; j += 256) {
      int idx = ((j & ~(h - 1)) << 1) | (j & (h - 1));
      float a = s[idx], b = s[idx + h];
      s[idx] = a + b;
      s[idx + h] = a - b;
    }
    __syncthreads();
  }
  const float sc = 1.0f / 65536.0f;  // (1/sqrt(4096)) * (1/1024)
  half4v* ov = (half4v*)(out + (size_t)blockIdx.x * 4096);
  for (int i = t; i < 1024; i += 256) {
    half4v h4;
    h4.x = (_Float16)(s[4 * i + 0] * sc);
    h4.y = (_Float16)(s[4 * i + 1] * sc);
    h4.z = (_Float16)(s[4 * i + 2] * sc);
    h4.w = (_Float16)(s[4 * i + 3] * sc);
    ov[i] = h4;
  }
}

// ---------------- 3. GEMM: Z = Xh @ W^T, 256^2 8-phase template -------------
__device__ __forceinline__ void gload16(const _Float16* g, _Float16* l) {
  __builtin_amdgcn_global_load_lds(
      (const __attribute__((address_space(1))) void*)g,
      (__attribute__((address_space(3))) void*)l, 16, 0, 0);
}

#define MF(a, b, c) __builtin_amdgcn_mfma_f32_16x16x32_f16(a, b, c, 0, 0, 0)

// swizzled ds_read: LDS[row][c] holds global (row, c ^ ((row&7)<<3))  [f16 units]
#define LDA(BUFI, M, KS) \
  (*(const half8*)&sA[BUFI][wm * 128 + (M) * 16 + fr][fc ^ ((KS) << 5)])
#define LDB(BUFI, Nn, KS) \
  (*(const half8*)&sB[BUFI][wn * 64 + (Nn) * 16 + fr][fc ^ ((KS) << 5)])

// stage one 128-row half-tile (2 x global_load_lds per thread, linear LDS dest,
// inverse-swizzled global source)
#define STAGE_A(BUFI, HALF, TILE)                                            \
  {                                                                          \
    const _Float16* s_ = gA + (long)(HALF) * 128 * K_DIM + (long)(TILE)*BK;  \
    _Float16* d_ = &sA[BUFI][(HALF)*128 + sr][scl];                          \
    gload16(s_, d_);                                                         \
    gload16(s_ + 64 * (long)K_DIM, d_ + 64 * BK);                            \
  }
#define STAGE_B(BUFI, HALF, TILE)                                            \
  {                                                                          \
    const _Float16* s_ = gB + (long)(HALF) * 128 * K_DIM + (long)(TILE)*BK;  \
    _Float16* d_ = &sB[BUFI][(HALF)*128 + sr][scl];                          \
    gload16(s_, d_);                                                         \
    gload16(s_ + 64 * (long)K_DIM, d_ + 64 * BK);                            \
  }

#define WAIT4 asm volatile("s_waitcnt vmcnt(4)" ::: "memory")
#define WAIT0 asm volatile("s_waitcnt vmcnt(0)" ::: "memory")

// one phase: 4 A-frag ds_reads | stage 1 half-tile | barrier | lgkm0 | 16 MFMA
#define PHASE(BUFI, M0, STAGE_STMT, TAIL_STMT)                               \
  {                                                                          \
    half8 x00 = LDA(BUFI, M0, 0);                                            \
    half8 x01 = LDA(BUFI, M0, 1);                                            \
    half8 x10 = LDA(BUFI, (M0) + 1, 0);                                      \
    half8 x11 = LDA(BUFI, (M0) + 1, 1);                                      \
    STAGE_STMT;                                                              \
    __builtin_amdgcn_s_barrier();                                            \
    asm volatile("s_waitcnt lgkmcnt(0)" ::: "memory");                       \
    __builtin_amdgcn_sched_barrier(0);                                       \
    __builtin_amdgcn_s_setprio(1);                                           \
    acc[M0][0] = MF(x00, bf[0][0], acc[M0][0]);                              \
    acc[M0][0] = MF(x01, bf[0][1], acc[M0][0]);                              \
    acc[M0][1] = MF(x00, bf[1][0], acc[M0][1]);                              \
    acc[M0][1] = MF(x01, bf[1][1], acc[M0][1]);                              \
    acc[M0][2] = MF(x00, bf[2][0], acc[M0][2]);                              \
    acc[M0][2] = MF(x01, bf[2][1], acc[M0][2]);                              \
    acc[M0][3] = MF(x00, bf[3][0], acc[M0][3]);                              \
    acc[M0][3] = MF(x01, bf[3][1], acc[M0][3]);                              \
    acc[(M0) + 1][0] = MF(x10, bf[0][0], acc[(M0) + 1][0]);                  \
    acc[(M0) + 1][0] = MF(x11, bf[0][1], acc[(M0) + 1][0]);                  \
    acc[(M0) + 1][1] = MF(x10, bf[1][0], acc[(M0) + 1][1]);                  \
    acc[(M0) + 1][1] = MF(x11, bf[1][1], acc[(M0) + 1][1]);                  \
    acc[(M0) + 1][2] = MF(x10, bf[2][0], acc[(M0) + 1][2]);                  \
    acc[(M0) + 1][2] = MF(x11, bf[2][1], acc[(M0) + 1][2]);                  \
    acc[(M0) + 1][3] = MF(x10, bf[3][0], acc[(M0) + 1][3]);                  \
    acc[(M0) + 1][3] = MF(x11, bf[3][1], acc[(M0) + 1][3]);                  \
    __builtin_amdgcn_s_setprio(0);                                           \
    TAIL_STMT;                                                               \
    __builtin_amdgcn_s_barrier();                                            \
  }

// one K-tile = 4 phases; phase 1 additionally reads all 8 B-frags (12 reads)
#define TILE(BUFI, S1, S2, S3, S4, TAILW)                                    \
  {                                                                          \
    half8 bf[4][2];                                                          \
    bf[0][0] = LDB(BUFI, 0, 0);                                              \
    bf[0][1] = LDB(BUFI, 0, 1);                                              \
    bf[1][0] = LDB(BUFI, 1, 0);                                              \
    bf[1][1] = LDB(BUFI, 1, 1);                                              \
    bf[2][0] = LDB(BUFI, 2, 0);                                              \
    bf[2][1] = LDB(BUFI, 2, 1);                                              \
    bf[3][0] = LDB(BUFI, 3, 0);                                              \
    bf[3][1] = LDB(BUFI, 3, 1);                                              \
    PHASE(BUFI, 0, S1, ;)                                                    \
    PHASE(BUFI, 2, S2, ;)                                                    \
    PHASE(BUFI, 4, S3, ;)                                                    \
    PHASE(BUFI, 6, S4, TAILW)                                                \
  }

__global__ __launch_bounds__(512) void gemm_kernel(
    const _Float16* __restrict__ A,   // [8192][4096] Xh
    const _Float16* __restrict__ B,   // [4096][4096] W (row-major over K)
    float* __restrict__ C) {          // [8192][4096]
  __shared__ _Float16 sA[2][BM][BK];  // 64 KB
  __shared__ _Float16 sB[2][BN][BK];  // 64 KB
  const int t = threadIdx.x;
  const int lane = t & 63;
  const int wave = t >> 6;
  const int wm = wave >> 2;  // 0..1  (2M x 4N wave grid)
  const int wn = wave & 3;   // 0..3

  // XCD-bijective swizzle: 512 wgs, 64 per XCD, consecutive wgs share bm
  const int bid = blockIdx.x;
  const int wg = (bid & 7) * 64 + (bid >> 3);
  const long bm = (long)(wg >> 4) * BM;  // 32 row-tiles
  const long bn = (long)(wg & 15) * BN;  // 16 col-tiles

  floatx4 acc[8][4];
#pragma unroll
  for (int i = 0; i < 8; i++)
#pragma unroll
    for (int j = 0; j < 4; j++) acc[i][j] = floatx4{0.f, 0.f, 0.f, 0.f};

  // staging constants: thread covers rows sr, sr+64 of a 128-row half-tile.
  // LDS dest linear (wave-uniform base + lane*16); global col pre-swizzled.
  const int sr = t >> 3;                          // 0..63
  const int scl = (t & 7) << 3;                   // linear LDS col (f16)
  const int sc = ((t & 7) ^ (sr & 7)) << 3;       // swizzled global col (f16)
  const _Float16* gA = A + (bm + sr) * (long)K_DIM + sc;
  const _Float16* gB = B + (bn + sr) * (long)K_DIM + sc;

  // fragment-read constants (16x16x32 f16 MFMA, m89-verified layout)
  const int fr = lane & 15;
  const int fc = (((lane >> 4) ^ (lane & 7)) << 3);  // ^ (ks<<5) per k-step

  // prologue: tile0 {A0,A1,B0,B1} + tile1 {B0,B1}; first 8 loads must land
  STAGE_A(0, 0, 0);
  STAGE_A(0, 1, 0);
  STAGE_B(0, 0, 0);
  STAGE_B(0, 1, 0);
  STAGE_B(1, 0, 1);
  STAGE_B(1, 1, 1);
  WAIT4;
  __builtin_amdgcn_s_barrier();

  // steady state: during tile t stage (t+1).A -> other buf (p1,p2) and
  // (t+2).B -> current buf (p3,p4; legal: all B reads of tile t are in p1).
  // WAIT4 at tile end leaves exactly the two B half-stages in flight.
#pragma unroll 1
  for (int kt = 0; kt < NTILES - 2; kt += 2) {
    TILE(0, STAGE_A(1, 0, kt + 1), STAGE_A(1, 1, kt + 1),
         STAGE_B(0, 0, kt + 2), STAGE_B(0, 1, kt + 2), WAIT4)
    TILE(1, STAGE_A(0, 0, kt + 2), STAGE_A(0, 1, kt + 2),
         STAGE_B(1, 0, kt + 3), STAGE_B(1, 1, kt + 3), WAIT4)
  }
  // tile 62: stage A of tile 63 only, then full drain; tile 63: no staging
  TILE(0, STAGE_A(1, 0, NTILES - 1), STAGE_A(1, 1, NTILES - 1), ;, ;, WAIT0)
  TILE(1, ;, ;, ;, ;, ;)

  // epilogue: C/D layout col=lane&15, row=(lane>>4)*4+reg [m89-verified]
  const int cn = lane & 15;
  const int cm4 = (lane >> 4) << 2;
#pragma unroll
  for (int m = 0; m < 8; m++) {
    const long row0 = bm + wm * 128 + m * 16 + cm4;
#pragma unroll
    for (int n = 0; n < 4; n++) {
      const long col = bn + wn * 64 + n * 16 + cn;
#pragma unroll
      for (int r = 0; r < 4; r++)
        C[(row0 + r) * (long)N_DIM + col] = (float)(_Float16)acc[m][n][r];
    }
  }
}

// ---------------- 4. fwht over Z rows (in-place), scale, *SV ----------------
__global__ __launch_bounds__(256) void fwht_out_kernel(
    float* __restrict__ z, const float* __restrict__ sv,
    const float* __restrict__ wscale) {
  __shared__ float s[4096];
  const int t = threadIdx.x;
  float4* zv = (float4*)(z + (size_t)blockIdx.x * 4096);
  for (int i = t; i < 1024; i += 256) {
    float4 v = zv[i];
    s[4 * i + 0] = v.x;
    s[4 * i + 1] = v.y;
    s[4 * i + 2] = v.z;
    s[4 * i + 3] = v.w;
  }
  __syncthreads();
  for (int h = 1; h < 4096; h <<= 1) {
    for (int j = t; j < 2048; j += 256) {
      int idx = ((j & ~(h - 1)) << 1) | (j & (h - 1));
      float a = s[idx], b = s[idx + h];
      s[idx] = a + b;
      s[idx + h] = a - b;
    }
    __syncthreads();
  }
  const float sc = wscale[0] * 16.0f;  // Wscale*1024 * (1/64)
  const float4* svv = (const float4*)sv;
  for (int i = t; i < 1024; i += 256) {
    float4 u = svv[i];
    float4 o;
    o.x = s[4 * i + 0] * sc * u.x;
    o.y = s[4 * i + 1] * sc * u.y;
    o.z = s[4 * i + 2] * sc * u.z;
    o.w = s[4 * i + 3] * sc * u.w;
    zv[i] = o;
  }
}

extern "C" void kernel_launch(void* const* d_in, const int* in_sizes, int n_in,
                              void* d_out, int out_size, void* d_ws, size_t ws_size,
                              hipStream_t stream) {
  const float* input = (const float*)d_in[0];
  const int* qidxs = (const int*)d_in[1];
  const float* su = (const float*)d_in[2];
  const float* sv = (const float*)d_in[3];
  const float* wscale = (const float*)d_in[4];
  const float4* cb = (const float4*)d_in[5];
  float* out = (float*)d_out;

  if (ws_size < 100663296ull) return;
  char* ws = (char*)d_ws;
  _Float16* W16 = (_Float16*)ws;                 // 32 MB f16
  _Float16* Xh = (_Float16*)(ws + 33554432ull);  // 64 MB f16

  decode_kernel<<<(4096 * 1024) / 256, 256, 0, stream>>>(qidxs, cb,
                                                         (half4v*)W16);
  fwht_in_kernel<<<B_ROWS, 256, 0, stream>>>(input, su, Xh);
  gemm_kernel<<<dim3((B_ROWS / BM) * (N_DIM / BN)), 512, 0, stream>>>(Xh, W16,
                                                                      out);
  fwht_out_kernel<<<B_ROWS, 256, 0, stream>>>(out, sv, wscale);
}

// Round 2
// 508.123 us; speedup vs baseline: 1.2520x; 1.0899x over previous
//
// R7: fwht_in/out rewritten as H16⊗H16⊗H16 (3 register-FWHT16 passes, 2
// XOR-swizzled LDS transposes, 2 barriers instead of 12). decode: 2 codes/thr.
// GEMM: MFMA order de-paired (k-slice-0 x8 then k-slice-1 x8) to break
// back-to-back acc dependencies. GEMM schedule otherwise unchanged (R6).
#include <hip/hip_runtime.h>
#include <hip/hip_fp16.h>

typedef _Float16 half8 __attribute__((ext_vector_type(8)));
typedef _Float16 half4v __attribute__((ext_vector_type(4)));
typedef float floatx4 __attribute__((ext_vector_type(4)));

#define K_DIM 4096   // inner dim (d_in)
#define N_DIM 4096   // output features (m)
#define B_ROWS 8192  // batch rows (4*2048)

#define BM 256
#define BN 256
#define BK 64
#define NTILES (K_DIM / BK)  // 64

// ---------------- 1. decode: W[j] = f16(D4_CB[Qidxs[j]]) --------------------
__global__ __launch_bounds__(256) void decode_kernel(
    const int2* __restrict__ qidxs, const float4* __restrict__ cb,
    half8* __restrict__ w) {
  int i = blockIdx.x * 256 + threadIdx.x;  // i in [0, 4096*1024/2)
  int2 q = qidxs[i];
  float4 v0 = cb[q.x];
  float4 v1 = cb[q.y];
  half8 h;
  h[0] = (_Float16)v0.x;
  h[1] = (_Float16)v0.y;
  h[2] = (_Float16)v0.z;
  h[3] = (_Float16)v0.w;
  h[4] = (_Float16)v1.x;
  h[5] = (_Float16)v1.y;
  h[6] = (_Float16)v1.z;
  h[7] = (_Float16)v1.w;
  w[i] = h;
}

// ---------------- register FWHT-16 (stages commute; bit order irrelevant) ---
__device__ __forceinline__ void fwht16(float v[16]) {
#pragma unroll
  for (int h = 1; h < 16; h <<= 1) {
#pragma unroll
    for (int g = 0; g < 16; g += 2 * h) {
#pragma unroll
      for (int j = g; j < g + h; ++j) {
        float a = v[j], b = v[j + h];
        v[j] = a + b;
        v[j + h] = a - b;
      }
    }
  }
}

// ---------------- 2. fwht over input rows -> f16 ----------------------------
// i = a*256 + c*16 + d. Pass1: FWHT16 over a (strides 256..2048).
// Pass2: over c (16..128). Pass3: over d (1..8). LDS col swizzle: c*16+(d^c)
// -> <=2-way bank aliasing on all passes (free).
__global__ __launch_bounds__(256) void fwht_in_kernel(
    const float* __restrict__ x, const float* __restrict__ su,
    _Float16* __restrict__ out) {
  __shared__ float s[16][264];
  const int t = threadIdx.x;
  const float* xr = x + (size_t)blockIdx.x * 4096;
  float v[16];
#pragma unroll
  for (int a = 0; a < 16; ++a) v[a] = xr[a * 256 + t] * su[a * 256 + t];
  fwht16(v);
  {
    const int c = t >> 4, d = t & 15;
    const int col = c * 16 + (d ^ c);
#pragma unroll
    for (int a = 0; a < 16; ++a) s[a][col] = v[a];
  }
  __syncthreads();
  const int a0 = t >> 4, d0 = t & 15;
#pragma unroll
  for (int c = 0; c < 16; ++c) v[c] = s[a0][c * 16 + (d0 ^ c)];
  fwht16(v);
#pragma unroll
  for (int c = 0; c < 16; ++c) s[a0][c * 16 + (d0 ^ c)] = v[c];
  __syncthreads();
  const int c1 = t & 15;
#pragma unroll
  for (int d = 0; d < 16; ++d) v[d] = s[a0][c1 * 16 + (d ^ c1)];
  fwht16(v);
  const float sc = 1.0f / 65536.0f;  // (1/sqrt(4096)) * (1/1024)
  half8 h0, h1;
#pragma unroll
  for (int d = 0; d < 8; ++d) h0[d] = (_Float16)(v[d] * sc);
#pragma unroll
  for (int d = 0; d < 8; ++d) h1[d] = (_Float16)(v[d + 8] * sc);
  half8* ov = (half8*)(out + (size_t)blockIdx.x * 4096 + t * 16);
  ov[0] = h0;
  ov[1] = h1;
}

// ---------------- 3. GEMM: Z = Xh @ W^T, 256^2 8-phase template -------------
__device__ __forceinline__ void gload16(const _Float16* g, _Float16* l) {
  __builtin_amdgcn_global_load_lds(
      (const __attribute__((address_space(1))) void*)g,
      (__attribute__((address_space(3))) void*)l, 16, 0, 0);
}

#define MF(a, b, c) __builtin_amdgcn_mfma_f32_16x16x32_f16(a, b, c, 0, 0, 0)

// swizzled ds_read: LDS[row][c] holds global (row, c ^ ((row&7)<<3))  [f16 units]
#define LDA(BUFI, M, KS) \
  (*(const half8*)&sA[BUFI][wm * 128 + (M) * 16 + fr][fc ^ ((KS) << 5)])
#define LDB(BUFI, Nn, KS) \
  (*(const half8*)&sB[BUFI][wn * 64 + (Nn) * 16 + fr][fc ^ ((KS) << 5)])

#define STAGE_A(BUFI, HALF, TILE)                                            \
  {                                                                          \
    const _Float16* s_ = gA + (long)(HALF) * 128 * K_DIM + (long)(TILE)*BK;  \
    _Float16* d_ = &sA[BUFI][(HALF)*128 + sr][scl];                          \
    gload16(s_, d_);                                                         \
    gload16(s_ + 64 * (long)K_DIM, d_ + 64 * BK);                            \
  }
#define STAGE_B(BUFI, HALF, TILE)                                            \
  {                                                                          \
    const _Float16* s_ = gB + (long)(HALF) * 128 * K_DIM + (long)(TILE)*BK;  \
    _Float16* d_ = &sB[BUFI][(HALF)*128 + sr][scl];                          \
    gload16(s_, d_);                                                         \
    gload16(s_ + 64 * (long)K_DIM, d_ + 64 * BK);                            \
  }

#define WAIT4 asm volatile("s_waitcnt vmcnt(4)" ::: "memory")
#define WAIT0 asm volatile("s_waitcnt vmcnt(0)" ::: "memory")

// one phase: 4 A-frag ds_reads | stage 1 half-tile | barrier | lgkm0 | 16 MFMA
// MFMA order: k-slice 0 for all 8 accs, then k-slice 1 (8 indep ops between
// the two updates of any acc -> no back-to-back MFMA dependency).
#define PHASE(BUFI, M0, STAGE_STMT, TAIL_STMT)                               \
  {                                                                          \
    half8 x00 = LDA(BUFI, M0, 0);                                            \
    half8 x01 = LDA(BUFI, M0, 1);                                            \
    half8 x10 = LDA(BUFI, (M0) + 1, 0);                                      \
    half8 x11 = LDA(BUFI, (M0) + 1, 1);                                      \
    STAGE_STMT;                                                              \
    __builtin_amdgcn_s_barrier();                                            \
    asm volatile("s_waitcnt lgkmcnt(0)" ::: "memory");                       \
    __builtin_amdgcn_sched_barrier(0);                                       \
    __builtin_amdgcn_s_setprio(1);                                           \
    acc[M0][0] = MF(x00, bf[0][0], acc[M0][0]);                              \
    acc[M0][1] = MF(x00, bf[1][0], acc[M0][1]);                              \
    acc[M0][2] = MF(x00, bf[2][0], acc[M0][2]);                              \
    acc[M0][3] = MF(x00, bf[3][0], acc[M0][3]);                              \
    acc[(M0) + 1][0] = MF(x10, bf[0][0], acc[(M0) + 1][0]);                  \
    acc[(M0) + 1][1] = MF(x10, bf[1][0], acc[(M0) + 1][1]);                  \
    acc[(M0) + 1][2] = MF(x10, bf[2][0], acc[(M0) + 1][2]);                  \
    acc[(M0) + 1][3] = MF(x10, bf[3][0], acc[(M0) + 1][3]);                  \
    acc[M0][0] = MF(x01, bf[0][1], acc[M0][0]);                              \
    acc[M0][1] = MF(x01, bf[1][1], acc[M0][1]);                              \
    acc[M0][2] = MF(x01, bf[2][1], acc[M0][2]);                              \
    acc[M0][3] = MF(x01, bf[3][1], acc[M0][3]);                              \
    acc[(M0) + 1][0] = MF(x11, bf[0][1], acc[(M0) + 1][0]);                  \
    acc[(M0) + 1][1] = MF(x11, bf[1][1], acc[(M0) + 1][1]);                  \
    acc[(M0) + 1][2] = MF(x11, bf[2][1], acc[(M0) + 1][2]);                  \
    acc[(M0) + 1][3] = MF(x11, bf[3][1], acc[(M0) + 1][3]);                  \
    __builtin_amdgcn_s_setprio(0);                                           \
    TAIL_STMT;                                                               \
    __builtin_amdgcn_s_barrier();                                            \
  }

#define TILE(BUFI, S1, S2, S3, S4, TAILW)                                    \
  {                                                                          \
    half8 bf[4][2];                                                          \
    bf[0][0] = LDB(BUFI, 0, 0);                                              \
    bf[0][1] = LDB(BUFI, 0, 1);                                              \
    bf[1][0] = LDB(BUFI, 1, 0);                                              \
    bf[1][1] = LDB(BUFI, 1, 1);                                              \
    bf[2][0] = LDB(BUFI, 2, 0);                                              \
    bf[2][1] = LDB(BUFI, 2, 1);                                              \
    bf[3][0] = LDB(BUFI, 3, 0);                                              \
    bf[3][1] = LDB(BUFI, 3, 1);                                              \
    PHASE(BUFI, 0, S1, ;)                                                    \
    PHASE(BUFI, 2, S2, ;)                                                    \
    PHASE(BUFI, 4, S3, ;)                                                    \
    PHASE(BUFI, 6, S4, TAILW)                                                \
  }

__global__ __launch_bounds__(512) void gemm_kernel(
    const _Float16* __restrict__ A,   // [8192][4096] Xh
    const _Float16* __restrict__ B,   // [4096][4096] W (row-major over K)
    float* __restrict__ C) {          // [8192][4096]
  __shared__ _Float16 sA[2][BM][BK];  // 64 KB
  __shared__ _Float16 sB[2][BN][BK];  // 64 KB
  const int t = threadIdx.x;
  const int lane = t & 63;
  const int wave = t >> 6;
  const int wm = wave >> 2;  // 0..1  (2M x 4N wave grid)
  const int wn = wave & 3;   // 0..3

  // XCD-bijective swizzle: 512 wgs, 64 per XCD, consecutive wgs share bm
  const int bid = blockIdx.x;
  const int wg = (bid & 7) * 64 + (bid >> 3);
  const long bm = (long)(wg >> 4) * BM;  // 32 row-tiles
  const long bn = (long)(wg & 15) * BN;  // 16 col-tiles

  floatx4 acc[8][4];
#pragma unroll
  for (int i = 0; i < 8; i++)
#pragma unroll
    for (int j = 0; j < 4; j++) acc[i][j] = floatx4{0.f, 0.f, 0.f, 0.f};

  const int sr = t >> 3;                          // 0..63
  const int scl = (t & 7) << 3;                   // linear LDS col (f16)
  const int sc = ((t & 7) ^ (sr & 7)) << 3;       // swizzled global col (f16)
  const _Float16* gA = A + (bm + sr) * (long)K_DIM + sc;
  const _Float16* gB = B + (bn + sr) * (long)K_DIM + sc;

  const int fr = lane & 15;
  const int fc = (((lane >> 4) ^ (lane & 7)) << 3);  // ^ (ks<<5) per k-step

  // prologue: tile0 {A0,A1,B0,B1} + tile1 {B0,B1}
  STAGE_A(0, 0, 0);
  STAGE_A(0, 1, 0);
  STAGE_B(0, 0, 0);
  STAGE_B(0, 1, 0);
  STAGE_B(1, 0, 1);
  STAGE_B(1, 1, 1);
  WAIT4;
  __builtin_amdgcn_s_barrier();

#pragma unroll 1
  for (int kt = 0; kt < NTILES - 2; kt += 2) {
    TILE(0, STAGE_A(1, 0, kt + 1), STAGE_A(1, 1, kt + 1),
         STAGE_B(0, 0, kt + 2), STAGE_B(0, 1, kt + 2), WAIT4)
    TILE(1, STAGE_A(0, 0, kt + 2), STAGE_A(0, 1, kt + 2),
         STAGE_B(1, 0, kt + 3), STAGE_B(1, 1, kt + 3), WAIT4)
  }
  TILE(0, STAGE_A(1, 0, NTILES - 1), STAGE_A(1, 1, NTILES - 1), ;, ;, WAIT0)
  TILE(1, ;, ;, ;, ;, ;)

  // epilogue: C/D layout col=lane&15, row=(lane>>4)*4+reg [m89-verified]
  const int cn = lane & 15;
  const int cm4 = (lane >> 4) << 2;
#pragma unroll
  for (int m = 0; m < 8; m++) {
    const long row0 = bm + wm * 128 + m * 16 + cm4;
#pragma unroll
    for (int n = 0; n < 4; n++) {
      const long col = bn + wn * 64 + n * 16 + cn;
#pragma unroll
      for (int r = 0; r < 4; r++)
        C[(row0 + r) * (long)N_DIM + col] = (float)(_Float16)acc[m][n][r];
    }
  }
}

// ---------------- 4. fwht over Z rows (in-place), scale, *SV ----------------
__global__ __launch_bounds__(256) void fwht_out_kernel(
    float* __restrict__ z, const float* __restrict__ sv,
    const float* __restrict__ wscale) {
  __shared__ float s[16][264];
  const int t = threadIdx.x;
  float* zr = z + (size_t)blockIdx.x * 4096;
  float v[16];
#pragma unroll
  for (int a = 0; a < 16; ++a) v[a] = zr[a * 256 + t];
  fwht16(v);
  {
    const int c = t >> 4, d = t & 15;
    const int col = c * 16 + (d ^ c);
#pragma unroll
    for (int a = 0; a < 16; ++a) s[a][col] = v[a];
  }
  __syncthreads();
  const int a0 = t >> 4, d0 = t & 15;
#pragma unroll
  for (int c = 0; c < 16; ++c) v[c] = s[a0][c * 16 + (d0 ^ c)];
  fwht16(v);
#pragma unroll
  for (int c = 0; c < 16; ++c) s[a0][c * 16 + (d0 ^ c)] = v[c];
  __syncthreads();
  const int c1 = t & 15;
#pragma unroll
  for (int d = 0; d < 16; ++d) v[d] = s[a0][c1 * 16 + (d ^ c1)];
  fwht16(v);
  const float scv = wscale[0] * 16.0f;  // Wscale*1024 * (1/64)
  const float4* svv = (const float4*)(sv + t * 16);
  float4* zo = (float4*)(zr + t * 16);
#pragma unroll
  for (int q = 0; q < 4; ++q) {
    float4 u = svv[q];
    float4 o;
    o.x = v[4 * q + 0] * scv * u.x;
    o.y = v[4 * q + 1] * scv * u.y;
    o.z = v[4 * q + 2] * scv * u.z;
    o.w = v[4 * q + 3] * scv * u.w;
    zo[q] = o;
  }
}

extern "C" void kernel_launch(void* const* d_in, const int* in_sizes, int n_in,
                              void* d_out, int out_size, void* d_ws, size_t ws_size,
                              hipStream_t stream) {
  const float* input = (const float*)d_in[0];
  const int* qidxs = (const int*)d_in[1];
  const float* su = (const float*)d_in[2];
  const float* sv = (const float*)d_in[3];
  const float* wscale = (const float*)d_in[4];
  const float4* cb = (const float4*)d_in[5];
  float* out = (float*)d_out;

  if (ws_size < 100663296ull) return;
  char* ws = (char*)d_ws;
  _Float16* W16 = (_Float16*)ws;                 // 32 MB f16
  _Float16* Xh = (_Float16*)(ws + 33554432ull);  // 64 MB f16

  decode_kernel<<<(4096 * 1024 / 2) / 256, 256, 0, stream>>>(
      (const int2*)qidxs, cb, (half8*)W16);
  fwht_in_kernel<<<B_ROWS, 256, 0, stream>>>(input, su, Xh);
  gemm_kernel<<<dim3((B_ROWS / BM) * (N_DIM / BN)), 512, 0, stream>>>(Xh, W16,
                                                                      out);
  fwht_out_kernel<<<B_ROWS, 256, 0, stream>>>(out, sv, wscale);
}

// Round 3
// 501.591 us; speedup vs baseline: 1.2683x; 1.0130x over previous
//
// R8: (1) fwht_in/out: d-axis pass FIRST -> contiguous float4 global I/O on
// both ends, 3 padded-LDS transposes (stride 265, <=2-way banks), register
// FWHT16s. (2) gemm epilogue: f16 C via per-wave LDS-staged transpose +
// coalesced dwordx4 stores (ref rounds z to f16 anyway); fwht_out reads f16.
// Runtime ws_size check picks f16 path (160 MB) or old f32 in-place fallback.
// GEMM K-loop schedule unchanged from R6/R7.
#include <hip/hip_runtime.h>
#include <hip/hip_fp16.h>

typedef _Float16 half8 __attribute__((ext_vector_type(8)));
typedef float floatx4 __attribute__((ext_vector_type(4)));

#define K_DIM 4096   // inner dim (d_in)
#define N_DIM 4096   // output features (m)
#define B_ROWS 8192  // batch rows (4*2048)

#define BM 256
#define BN 256
#define BK 64
#define NTILES (K_DIM / BK)  // 64

// ---------------- 1. decode: W[j] = f16(D4_CB[Qidxs[j]]) --------------------
__global__ __launch_bounds__(256) void decode_kernel(
    const int2* __restrict__ qidxs, const float4* __restrict__ cb,
    half8* __restrict__ w) {
  int i = blockIdx.x * 256 + threadIdx.x;
  int2 q = qidxs[i];
  float4 v0 = cb[q.x];
  float4 v1 = cb[q.y];
  half8 h;
  h[0] = (_Float16)v0.x;
  h[1] = (_Float16)v0.y;
  h[2] = (_Float16)v0.z;
  h[3] = (_Float16)v0.w;
  h[4] = (_Float16)v1.x;
  h[5] = (_Float16)v1.y;
  h[6] = (_Float16)v1.z;
  h[7] = (_Float16)v1.w;
  w[i] = h;
}

// ---------------- register FWHT-16 (stages commute) -------------------------
__device__ __forceinline__ void fwht16(float v[16]) {
#pragma unroll
  for (int h = 1; h < 16; h <<= 1) {
#pragma unroll
    for (int g = 0; g < 16; g += 2 * h) {
#pragma unroll
      for (int j = g; j < g + h; ++j) {
        float a = v[j], b = v[j + h];
        v[j] = a + b;
        v[j + h] = a - b;
      }
    }
  }
}

// 3-pass FWHT-4096 core over LDS s[16*265]; i = a*256 + c*16 + d.
// Entry: thread t holds v[d] for (a,c) = (t>>4, t&15)  [contiguous block].
// Exit:  same ownership, fully transformed (all three H16 passes applied).
// Element (a,c,d) lives at s[a*265 + c*16 + (d^c)]; stride 265 (mod 32 = 9)
// rotates banks across a; d^c rotates within the 16-block across c.
__device__ __forceinline__ void fwht4096(float v[16], float* s, int t) {
  const int a0 = t >> 4, c0 = t & 15;
  fwht16(v);  // over d
#pragma unroll
  for (int d = 0; d < 16; ++d) s[a0 * 265 + c0 * 16 + (d ^ c0)] = v[d];
  __syncthreads();
  const int d1 = t & 15;  // thread now (a, d) = (a0, d1)
#pragma unroll
  for (int c = 0; c < 16; ++c) v[c] = s[a0 * 265 + c * 16 + (d1 ^ c)];
  fwht16(v);  // over c
#pragma unroll
  for (int c = 0; c < 16; ++c) s[a0 * 265 + c * 16 + (d1 ^ c)] = v[c];
  __syncthreads();
  const int c2 = t >> 4, d2 = t & 15;  // thread now (c, d)
#pragma unroll
  for (int a = 0; a < 16; ++a) v[a] = s[a * 265 + c2 * 16 + (d2 ^ c2)];
  fwht16(v);  // over a
#pragma unroll
  for (int a = 0; a < 16; ++a) s[a * 265 + c2 * 16 + (d2 ^ c2)] = v[a];
  __syncthreads();
  // gather back to contiguous ownership
#pragma unroll
  for (int d = 0; d < 16; ++d) v[d] = s[a0 * 265 + c0 * 16 + (d ^ c0)];
}

// ---------------- 2. fwht over input rows -> f16 ----------------------------
__global__ __launch_bounds__(256) void fwht_in_kernel(
    const float* __restrict__ x, const float* __restrict__ su,
    _Float16* __restrict__ out) {
  __shared__ float s[16 * 265];
  const int t = threadIdx.x;
  const float4* xv = (const float4*)(x + (size_t)blockIdx.x * 4096 + t * 16);
  const float4* uv = (const float4*)(su + t * 16);
  float v[16];
#pragma unroll
  for (int q = 0; q < 4; ++q) {
    float4 a = xv[q], b = uv[q];
    v[4 * q + 0] = a.x * b.x;
    v[4 * q + 1] = a.y * b.y;
    v[4 * q + 2] = a.z * b.z;
    v[4 * q + 3] = a.w * b.w;
  }
  fwht4096(v, s, t);
  const float sc = 1.0f / 65536.0f;  // (1/sqrt(4096)) * (1/1024)
  half8 h0, h1;
#pragma unroll
  for (int d = 0; d < 8; ++d) h0[d] = (_Float16)(v[d] * sc);
#pragma unroll
  for (int d = 0; d < 8; ++d) h1[d] = (_Float16)(v[d + 8] * sc);
  half8* ov = (half8*)(out + (size_t)blockIdx.x * 4096 + t * 16);
  ov[0] = h0;
  ov[1] = h1;
}

// ---------------- 3. GEMM: Z = Xh @ W^T, 256^2 8-phase template -------------
__device__ __forceinline__ void gload16(const _Float16* g, _Float16* l) {
  __builtin_amdgcn_global_load_lds(
      (const __attribute__((address_space(1))) void*)g,
      (__attribute__((address_space(3))) void*)l, 16, 0, 0);
}

#define MF(a, b, c) __builtin_amdgcn_mfma_f32_16x16x32_f16(a, b, c, 0, 0, 0)

#define LDA(BUFI, M, KS) \
  (*(const half8*)&sA[BUFI][wm * 128 + (M) * 16 + fr][fc ^ ((KS) << 5)])
#define LDB(BUFI, Nn, KS) \
  (*(const half8*)&sB[BUFI][wn * 64 + (Nn) * 16 + fr][fc ^ ((KS) << 5)])

#define STAGE_A(BUFI, HALF, TILE)                                            \
  {                                                                          \
    const _Float16* s_ = gA + (long)(HALF) * 128 * K_DIM + (long)(TILE)*BK;  \
    _Float16* d_ = &sA[BUFI][(HALF)*128 + sr][scl];                          \
    gload16(s_, d_);                                                         \
    gload16(s_ + 64 * (long)K_DIM, d_ + 64 * BK);                            \
  }
#define STAGE_B(BUFI, HALF, TILE)                                            \
  {                                                                          \
    const _Float16* s_ = gB + (long)(HALF) * 128 * K_DIM + (long)(TILE)*BK;  \
    _Float16* d_ = &sB[BUFI][(HALF)*128 + sr][scl];                          \
    gload16(s_, d_);                                                         \
    gload16(s_ + 64 * (long)K_DIM, d_ + 64 * BK);                            \
  }

#define WAIT4 asm volatile("s_waitcnt vmcnt(4)" ::: "memory")
#define WAIT0 asm volatile("s_waitcnt vmcnt(0)" ::: "memory")

#define PHASE(BUFI, M0, STAGE_STMT, TAIL_STMT)                               \
  {                                                                          \
    half8 x00 = LDA(BUFI, M0, 0);                                            \
    half8 x01 = LDA(BUFI, M0, 1);                                            \
    half8 x10 = LDA(BUFI, (M0) + 1, 0);                                      \
    half8 x11 = LDA(BUFI, (M0) + 1, 1);                                      \
    STAGE_STMT;                                                              \
    __builtin_amdgcn_s_barrier();                                            \
    asm volatile("s_waitcnt lgkmcnt(0)" ::: "memory");                       \
    __builtin_amdgcn_sched_barrier(0);                                       \
    __builtin_amdgcn_s_setprio(1);                                           \
    acc[M0][0] = MF(x00, bf[0][0], acc[M0][0]);                              \
    acc[M0][1] = MF(x00, bf[1][0], acc[M0][1]);                              \
    acc[M0][2] = MF(x00, bf[2][0], acc[M0][2]);                              \
    acc[M0][3] = MF(x00, bf[3][0], acc[M0][3]);                              \
    acc[(M0) + 1][0] = MF(x10, bf[0][0], acc[(M0) + 1][0]);                  \
    acc[(M0) + 1][1] = MF(x10, bf[1][0], acc[(M0) + 1][1]);                  \
    acc[(M0) + 1][2] = MF(x10, bf[2][0], acc[(M0) + 1][2]);                  \
    acc[(M0) + 1][3] = MF(x10, bf[3][0], acc[(M0) + 1][3]);                  \
    acc[M0][0] = MF(x01, bf[0][1], acc[M0][0]);                              \
    acc[M0][1] = MF(x01, bf[1][1], acc[M0][1]);                              \
    acc[M0][2] = MF(x01, bf[2][1], acc[M0][2]);                              \
    acc[M0][3] = MF(x01, bf[3][1], acc[M0][3]);                              \
    acc[(M0) + 1][0] = MF(x11, bf[0][1], acc[(M0) + 1][0]);                  \
    acc[(M0) + 1][1] = MF(x11, bf[1][1], acc[(M0) + 1][1]);                  \
    acc[(M0) + 1][2] = MF(x11, bf[2][1], acc[(M0) + 1][2]);                  \
    acc[(M0) + 1][3] = MF(x11, bf[3][1], acc[(M0) + 1][3]);                  \
    __builtin_amdgcn_s_setprio(0);                                           \
    TAIL_STMT;                                                               \
    __builtin_amdgcn_s_barrier();                                            \
  }

#define TILE(BUFI, S1, S2, S3, S4, TAILW)                                    \
  {                                                                          \
    half8 bf[4][2];                                                          \
    bf[0][0] = LDB(BUFI, 0, 0);                                              \
    bf[0][1] = LDB(BUFI, 0, 1);                                              \
    bf[1][0] = LDB(BUFI, 1, 0);                                              \
    bf[1][1] = LDB(BUFI, 1, 1);                                              \
    bf[2][0] = LDB(BUFI, 2, 0);                                              \
    bf[2][1] = LDB(BUFI, 2, 1);                                              \
    bf[3][0] = LDB(BUFI, 3, 0);                                              \
    bf[3][1] = LDB(BUFI, 3, 1);                                              \
    PHASE(BUFI, 0, S1, ;)                                                    \
    PHASE(BUFI, 2, S2, ;)                                                    \
    PHASE(BUFI, 4, S3, ;)                                                    \
    PHASE(BUFI, 6, S4, TAILW)                                                \
  }

template <bool OUT_F16>
__global__ __launch_bounds__(512) void gemm_kernel(
    const _Float16* __restrict__ A,  // [8192][4096] Xh
    const _Float16* __restrict__ B,  // [4096][4096] W (row-major over K)
    void* __restrict__ C) {          // f16 [8192][4096] or f32 [8192][4096]
  __shared__ _Float16 sA[2][BM][BK];  // 64 KB
  __shared__ _Float16 sB[2][BN][BK];  // 64 KB
  const int t = threadIdx.x;
  const int lane = t & 63;
  const int wave = t >> 6;
  const int wm = wave >> 2;  // 0..1  (2M x 4N wave grid)
  const int wn = wave & 3;   // 0..3

  const int bid = blockIdx.x;
  const int wg = (bid & 7) * 64 + (bid >> 3);
  const long bm = (long)(wg >> 4) * BM;
  const long bn = (long)(wg & 15) * BN;

  floatx4 acc[8][4];
#pragma unroll
  for (int i = 0; i < 8; i++)
#pragma unroll
    for (int j = 0; j < 4; j++) acc[i][j] = floatx4{0.f, 0.f, 0.f, 0.f};

  const int sr = t >> 3;
  const int scl = (t & 7) << 3;
  const int sc = ((t & 7) ^ (sr & 7)) << 3;
  const _Float16* gA = A + (bm + sr) * (long)K_DIM + sc;
  const _Float16* gB = B + (bn + sr) * (long)K_DIM + sc;

  const int fr = lane & 15;
  const int fc = (((lane >> 4) ^ (lane & 7)) << 3);

  STAGE_A(0, 0, 0);
  STAGE_A(0, 1, 0);
  STAGE_B(0, 0, 0);
  STAGE_B(0, 1, 0);
  STAGE_B(1, 0, 1);
  STAGE_B(1, 1, 1);
  WAIT4;
  __builtin_amdgcn_s_barrier();

#pragma unroll 1
  for (int kt = 0; kt < NTILES - 2; kt += 2) {
    TILE(0, STAGE_A(1, 0, kt + 1), STAGE_A(1, 1, kt + 1),
         STAGE_B(0, 0, kt + 2), STAGE_B(0, 1, kt + 2), WAIT4)
    TILE(1, STAGE_A(0, 0, kt + 2), STAGE_A(0, 1, kt + 2),
         STAGE_B(1, 0, kt + 3), STAGE_B(1, 1, kt + 3), WAIT4)
  }
  TILE(0, STAGE_A(1, 0, NTILES - 1), STAGE_A(1, 1, NTILES - 1), ;, ;, WAIT0)
  TILE(1, ;, ;, ;, ;, ;)

  const int cn = lane & 15;
  const int cm4 = (lane >> 4) << 2;
  if (OUT_F16) {
    // LDS-staged coalesced f16 epilogue. Per-wave 16 KB patch (128x64 f16),
    // 16B-chunk XOR swizzle (chunk ^= row&7) -> conflict-free b128 readback.
    __syncthreads();  // all waves past final K-loop reads of sA/sB
    _Float16* patch =
        ((wave < 4) ? (_Float16*)sA : (_Float16*)sB) + (wave & 3) * 8192;
#pragma unroll
    for (int m = 0; m < 8; m++)
#pragma unroll
      for (int n = 0; n < 4; n++)
#pragma unroll
        for (int r = 0; r < 4; r++) {
          int rl = m * 16 + cm4 + r, cl = n * 16 + cn;
          patch[rl * 64 + (((cl >> 3) ^ (rl & 7)) << 3) + (cl & 7)] =
              (_Float16)acc[m][n][r];
        }
    asm volatile("s_waitcnt lgkmcnt(0)" ::: "memory");
    __builtin_amdgcn_sched_barrier(0);
    _Float16* Co = (_Float16*)C;
#pragma unroll
    for (int p = 0; p < 16; p++) {
      int rl = p * 8 + (lane >> 3);
      int c8 = lane & 7;
      half8 val = *(const half8*)(patch + rl * 64 + ((c8 ^ (rl & 7)) << 3));
      *(half8*)(Co + (bm + wm * 128 + rl) * (long)N_DIM + bn + wn * 64 +
                c8 * 8) = val;
    }
  } else {
    float* Cf = (float*)C;
#pragma unroll
    for (int m = 0; m < 8; m++) {
      const long row0 = bm + wm * 128 + m * 16 + cm4;
#pragma unroll
      for (int n = 0; n < 4; n++) {
        const long col = bn + wn * 64 + n * 16 + cn;
#pragma unroll
        for (int r = 0; r < 4; r++)
          Cf[(row0 + r) * (long)N_DIM + col] = (float)(_Float16)acc[m][n][r];
      }
    }
  }
}

// ---------------- 4. fwht over Z rows, scale, *SV ---------------------------
template <bool F16IN>
__global__ __launch_bounds__(256) void fwht_out_kernel(
    const void* __restrict__ zin, float* __restrict__ zout,
    const float* __restrict__ sv, const float* __restrict__ wscale) {
  __shared__ float s[16 * 265];
  const int t = threadIdx.x;
  float v[16];
  if (F16IN) {
    const half8* zv =
        (const half8*)((const _Float16*)zin + (size_t)blockIdx.x * 4096 +
                       t * 16);
    half8 h0 = zv[0], h1 = zv[1];
#pragma unroll
    for (int d = 0; d < 8; ++d) v[d] = (float)h0[d];
#pragma unroll
    for (int d = 0; d < 8; ++d) v[d + 8] = (float)h1[d];
  } else {
    const float4* zv =
        (const float4*)((const float*)zin + (size_t)blockIdx.x * 4096 +
                        t * 16);
#pragma unroll
    for (int q = 0; q < 4; ++q) {
      float4 a = zv[q];
      v[4 * q + 0] = a.x;
      v[4 * q + 1] = a.y;
      v[4 * q + 2] = a.z;
      v[4 * q + 3] = a.w;
    }
  }
  fwht4096(v, s, t);
  const float scv = wscale[0] * 16.0f;  // Wscale*1024 * (1/64)
  const float4* svv = (const float4*)(sv + t * 16);
  float4* zo = (float4*)(zout + (size_t)blockIdx.x * 4096 + t * 16);
#pragma unroll
  for (int q = 0; q < 4; ++q) {
    float4 u = svv[q];
    float4 o;
    o.x = v[4 * q + 0] * scv * u.x;
    o.y = v[4 * q + 1] * scv * u.y;
    o.z = v[4 * q + 2] * scv * u.z;
    o.w = v[4 * q + 3] * scv * u.w;
    zo[q] = o;
  }
}

extern "C" void kernel_launch(void* const* d_in, const int* in_sizes, int n_in,
                              void* d_out, int out_size, void* d_ws,
                              size_t ws_size, hipStream_t stream) {
  const float* input = (const float*)d_in[0];
  const int* qidxs = (const int*)d_in[1];
  const float* su = (const float*)d_in[2];
  const float* sv = (const float*)d_in[3];
  const float* wscale = (const float*)d_in[4];
  const float4* cb = (const float4*)d_in[5];
  float* out = (float*)d_out;

  if (ws_size < 100663296ull) return;
  char* ws = (char*)d_ws;
  _Float16* W16 = (_Float16*)ws;                  // 32 MB f16
  _Float16* Xh = (_Float16*)(ws + 33554432ull);   // 64 MB f16
  _Float16* Zh = (_Float16*)(ws + 100663296ull);  // 64 MB f16 (optional)
  const bool f16path = ws_size >= 167772160ull;

  decode_kernel<<<(4096 * 1024 / 2) / 256, 256, 0, stream>>>(
      (const int2*)qidxs, cb, (half8*)W16);
  fwht_in_kernel<<<B_ROWS, 256, 0, stream>>>(input, su, Xh);
  if (f16path) {
    gemm_kernel<true><<<dim3((B_ROWS / BM) * (N_DIM / BN)), 512, 0, stream>>>(
        Xh, W16, (void*)Zh);
    fwht_out_kernel<true><<<B_ROWS, 256, 0, stream>>>((const void*)Zh, out, sv,
                                                      wscale);
  } else {
    gemm_kernel<false><<<dim3((B_ROWS / BM) * (N_DIM / BN)), 512, 0, stream>>>(
        Xh, W16, (void*)out);
    fwht_out_kernel<false><<<B_ROWS, 256, 0, stream>>>((const void*)out, out,
                                                       sv, wscale);
  }
}